// Round 16
// baseline (2519.437 us; speedup 1.0000x reference)
//
#include <hip/hip_runtime.h>
#include <cstdint>
#include <cstddef>

#define DM 1024
#define HN 16
#define DH 64
#define BB 4
#define SS 2048
#define MM (BB * SS)  // 8192

typedef __bf16 bf16;
typedef bf16 bf16x8 __attribute__((ext_vector_type(8)));
typedef bf16 bf16x4 __attribute__((ext_vector_type(4)));
typedef float f32x4 __attribute__((ext_vector_type(4)));
typedef int i32x4 __attribute__((ext_vector_type(4)));

__device__ __forceinline__ f32x4 mfma16(bf16x8 a, bf16x8 b, f32x4 c) {
  return __builtin_amdgcn_mfma_f32_16x16x32_bf16(a, b, c, 0, 0, 0);
}

typedef __attribute__((address_space(3))) void lds_void_t;
typedef __attribute__((address_space(1))) void glob_void_t;

__device__ __forceinline__ void gload16(const void* g, void* l) {
  __builtin_amdgcn_global_load_lds((const glob_void_t*)g, (lds_void_t*)l, 16, 0, 0);
}

// ------- transposed mask bitmask: mT[b][qt][col] bit r = mask[b][qt*32+r][col] -------
__global__ __launch_bounds__(256) void mask_bitsT(const int* __restrict__ mask,
                                                  unsigned int* __restrict__ mT) {
  int qt = blockIdx.x, b = blockIdx.y;
  int col0 = threadIdx.x * 8;
  unsigned int m[8] = {0, 0, 0, 0, 0, 0, 0, 0};
  const int* mp = mask + ((size_t)b * SS + qt * 32) * SS + col0;
  for (int r = 0; r < 32; ++r) {
    i32x4 a = *(const i32x4*)(mp + (size_t)r * SS);
    i32x4 c = *(const i32x4*)(mp + (size_t)r * SS + 4);
#pragma unroll
    for (int i = 0; i < 4; ++i) {
      m[i] |= (unsigned int)(a[i] != 0) << r;
      m[4 + i] |= (unsigned int)(c[i] != 0) << r;
    }
  }
#pragma unroll
  for (int i = 0; i < 8; ++i)
    mT[((size_t)b * 64 + qt) * SS + col0 + i] = m[i];
}

// ---------------- fp32 -> bf16 convert, 3 tensors in one launch ----------------
__global__ __launch_bounds__(256) void cvt3(const float* __restrict__ q,
                                            const float* __restrict__ k,
                                            const float* __restrict__ v,
                                            bf16* __restrict__ dst) {
  int which = blockIdx.y;
  const float* in = which == 0 ? q : which == 1 ? k : v;
  bf16* out = dst + (size_t)which * MM * DM;
  int i = (blockIdx.x * 256 + threadIdx.x) * 8;
  f32x4 a = *(const f32x4*)(in + i);
  f32x4 b = *(const f32x4*)(in + i + 4);
  bf16x8 o;
  o[0] = (bf16)a[0]; o[1] = (bf16)a[1]; o[2] = (bf16)a[2]; o[3] = (bf16)a[3];
  o[4] = (bf16)b[0]; o[5] = (bf16)b[1]; o[6] = (bf16)b[2]; o[7] = (bf16)b[3];
  *(bf16x8*)(out + i) = o;
}

// ------------- weight transpose+convert, 4 weights: WT[p*1024+n][k] = Wp[k][n] -------------
__global__ __launch_bounds__(256) void wtrans4(const float* __restrict__ w_q,
                                               const float* __restrict__ w_k,
                                               const float* __restrict__ w_v,
                                               const float* __restrict__ w_fc,
                                               bf16* __restrict__ WT) {
  int p = blockIdx.z;
  const float* W = p == 0 ? w_q : p == 1 ? w_k : p == 2 ? w_v : w_fc;
  bf16* out = WT + (size_t)p * DM * DM;
  __shared__ float t[32][33];
  int n0 = blockIdx.x * 32, k0 = blockIdx.y * 32;
  int tid = threadIdx.x;
  int r = tid >> 3, c = (tid & 7) * 4;
  f32x4 v = *(const f32x4*)&W[(size_t)(k0 + r) * DM + n0 + c];
  t[r][c] = v[0]; t[r][c + 1] = v[1]; t[r][c + 2] = v[2]; t[r][c + 3] = v[3];
  __syncthreads();
  bf16x4 o;
#pragma unroll
  for (int i = 0; i < 4; ++i) o[i] = (bf16)t[c + i][r];
  *(bf16x4*)&out[(size_t)(n0 + r) * DM + k0 + c] = o;
}

// ---------------- fused QKV projection GEMM (N=3072) ----------------
// proj 0 (Q): head layout [bh][s][d], *0.125
// proj 1 (K): head layout [bh][s][d]
// proj 2 (V): TILED transposed layout [bh][s/32][d][s%32]
__global__ __launch_bounds__(256) void gemm_qkv(const bf16* __restrict__ Abase,
                                                const bf16* __restrict__ Bt,
                                                const float* __restrict__ b_q,
                                                const float* __restrict__ b_k,
                                                const float* __restrict__ b_v,
                                                bf16* __restrict__ qhh,
                                                bf16* __restrict__ khh,
                                                bf16* __restrict__ vhT) {
  constexpr int K = DM;
  __shared__ bf16 Ab[128 * 32];
  __shared__ bf16 Bb[128 * 32];
  int tid = threadIdx.x, wave = tid >> 6, lane = tid & 63;
  int bm = blockIdx.x * 128, bn = blockIdx.y * 128;
  int proj = bn >> 10;
  const bf16* A = Abase + (size_t)proj * MM * DM;
  const float* bias = proj == 0 ? b_q : proj == 1 ? b_k : b_v;
  int wr = (wave >> 1) * 64, wc = (wave & 1) * 64;
  int fr = lane & 15, kg8 = (lane >> 4) * 8;
  f32x4 acc[4][4] = {};
  int arow = tid >> 2, acol = (tid & 3) * 8;
  const bf16* Ag0 = A + (size_t)(bm + arow) * K + acol;
  const bf16* Ag1 = Ag0 + (size_t)64 * K;
  const bf16* Bg0 = Bt + (size_t)(bn + arow) * K + acol;
  const bf16* Bg1 = Bg0 + (size_t)64 * K;
  char* la = (char*)Ab + wave * 1024;
  char* lb = (char*)Bb + wave * 1024;
  for (int k0 = 0; k0 < K; k0 += 32) {
    __syncthreads();
    gload16(Ag0 + k0, la);
    gload16(Ag1 + k0, la + 4096);
    gload16(Bg0 + k0, lb);
    gload16(Bg1 + k0, lb + 4096);
    asm volatile("s_waitcnt vmcnt(0)" ::: "memory");
    __syncthreads();
    bf16x8 af[4], bfr[4];
#pragma unroll
    for (int m = 0; m < 4; ++m)
      af[m] = *(const bf16x8*)&Ab[(wr + m * 16 + fr) * 32 + kg8];
#pragma unroll
    for (int n = 0; n < 4; ++n)
      bfr[n] = *(const bf16x8*)&Bb[(wc + n * 16 + fr) * 32 + kg8];
#pragma unroll
    for (int m = 0; m < 4; ++m)
#pragma unroll
      for (int n = 0; n < 4; ++n) acc[m][n] = mfma16(af[m], bfr[n], acc[m][n]);
  }
  int b = bm >> 11;
#pragma unroll
  for (int m = 0; m < 4; ++m)
#pragma unroll
    for (int n = 0; n < 4; ++n) {
      int c = bn + wc + n * 16 + fr;
      int lc = c & 1023;
      float bv = bias[lc];
      int h = lc >> 6, d = lc & 63;
      int r0 = bm + wr + m * 16 + (lane >> 4) * 4;
      int s0 = r0 & (SS - 1);
      if (proj == 2) {
        bf16x4 o;
#pragma unroll
        for (int j = 0; j < 4; ++j) o[j] = (bf16)(acc[m][n][j] + bv);
        *(bf16x4*)&vhT[(size_t)(b * HN + h) * (SS * DH) +
                       (size_t)(s0 >> 5) * (DH * 32) + d * 32 + (s0 & 31)] = o;
      } else {
        bf16* dst = proj == 0 ? qhh : khh;
        float sc = proj == 0 ? 0.125f : 1.f;
#pragma unroll
        for (int j = 0; j < 4; ++j) {
          float v = (acc[m][n][j] + bv) * sc;
          dst[(size_t)(b * HN + h) * (SS * DH) + (size_t)(s0 + j) * DH + d] =
              (bf16)v;
        }
      }
    }
}

// ---------------- out-proj GEMM: fp32 out + bias + residual ----------------
__global__ __launch_bounds__(256) void gemm_out(const bf16* __restrict__ A,
                                                const bf16* __restrict__ Bt,
                                                const float* __restrict__ bias,
                                                const float* __restrict__ resid,
                                                float* __restrict__ out) {
  constexpr int K = DM;
  __shared__ bf16 Ab[128 * 32];
  __shared__ bf16 Bb[128 * 32];
  int tid = threadIdx.x, wave = tid >> 6, lane = tid & 63;
  int bm = blockIdx.x * 128, bn = blockIdx.y * 128;
  int wr = (wave >> 1) * 64, wc = (wave & 1) * 64;
  int fr = lane & 15, kg8 = (lane >> 4) * 8;
  f32x4 acc[4][4] = {};
  int arow = tid >> 2, acol = (tid & 3) * 8;
  const bf16* Ag0 = A + (size_t)(bm + arow) * K + acol;
  const bf16* Ag1 = Ag0 + (size_t)64 * K;
  const bf16* Bg0 = Bt + (size_t)(bn + arow) * K + acol;
  const bf16* Bg1 = Bg0 + (size_t)64 * K;
  char* la = (char*)Ab + wave * 1024;
  char* lb = (char*)Bb + wave * 1024;
  for (int k0 = 0; k0 < K; k0 += 32) {
    __syncthreads();
    gload16(Ag0 + k0, la);
    gload16(Ag1 + k0, la + 4096);
    gload16(Bg0 + k0, lb);
    gload16(Bg1 + k0, lb + 4096);
    asm volatile("s_waitcnt vmcnt(0)" ::: "memory");
    __syncthreads();
    bf16x8 af[4], bfr[4];
#pragma unroll
    for (int m = 0; m < 4; ++m)
      af[m] = *(const bf16x8*)&Ab[(wr + m * 16 + fr) * 32 + kg8];
#pragma unroll
    for (int n = 0; n < 4; ++n)
      bfr[n] = *(const bf16x8*)&Bb[(wc + n * 16 + fr) * 32 + kg8];
#pragma unroll
    for (int m = 0; m < 4; ++m)
#pragma unroll
      for (int n = 0; n < 4; ++n) acc[m][n] = mfma16(af[m], bfr[n], acc[m][n]);
  }
#pragma unroll
  for (int m = 0; m < 4; ++m)
#pragma unroll
    for (int n = 0; n < 4; ++n) {
      int c = bn + wc + n * 16 + fr;
      float bv = bias[c];
#pragma unroll
      for (int j = 0; j < 4; ++j) {
        int r = bm + wr + m * 16 + (lane >> 4) * 4 + j;
        size_t idx = (size_t)r * DM + c;
        out[idx] = acc[m][n][j] + bv + resid[idx];
      }
    }
}

// ---------------- fused attention: 2 q-tiles per block, guaranteed store overlap ----------------
// grid: 2048 blocks 1D (XCD-swizzled), 1024 threads.
// LDS: 32*4096 probs + 8192 pbuf + 128 invp (reused across the 2 sub-tiles).
// Per sub-tile: QK^T(+masked exp) -> rowsum -> PV(+setprio, V-prefetch) -> ctx ->
// store-issue. The next sub-tile's compute overlaps the prior store drain.
__global__ __launch_bounds__(1024, 4) void attn_kernel(
    const bf16* __restrict__ qh, const bf16* __restrict__ kh,
    const bf16* __restrict__ vhT, const unsigned int* __restrict__ mT,
    float* __restrict__ attn_out, bf16* __restrict__ ctx) {
  extern __shared__ char smem[];
  float* pbuf = (float*)(smem + 32 * 4096);
  float* invp = (float*)(smem + 32 * 4096 + 8192);
  int tid = threadIdx.x, wave = tid >> 6, lane = tid & 63;
  // XCD-aware bijective swizzle: 2048 = 8 XCDs x 256; consecutive fids share bh
  int fid = (blockIdx.x & 7) * 256 + (blockIdx.x >> 3);
  int bh = fid >> 5, qtp = fid & 31;
  int b = bh >> 4, h = bh & 15;
  const bf16* kbase = kh + (size_t)bh * SS * DH;
  const bf16* vbase = vhT + (size_t)bh * SS * DH;  // tiled [s/32][64][32]
  int fr = lane & 15, kg = lane >> 4;
  int rb = wave >> 3, dq = (wave >> 1) & 3, kh2 = wave & 1;
  int prow_row = rb * 16 + fr;
  char* prow = smem + prow_row * 4096;

  for (int sub = 0; sub < 2; ++sub) {
    int qt = qtp * 2 + sub;
    int q0 = qt * 32;
    const bf16* qbase = qh + ((size_t)bh * SS + q0) * DH;
    const unsigned int* mTb = mT + ((size_t)b * 64 + qt) * SS;

    const bf16* vtile = vbase + (size_t)(kh2 * 32) * (DH * 32) +
                        (dq * 16 + fr) * 32 + kg * 8;
    bf16x8 vb[8], pb[8];
    auto vbload = [&](int kk) {
      vb[kk & 7] = *(const bf16x8*)&vtile[(size_t)kk * (DH * 32)];
    };
    auto pbload = [&](int kk) {
      int slotA = kh2 * 128 + kk * 4 + kg;
      pb[kk & 7] = *(const bf16x8*)(prow + ((slotA ^ prow_row) << 4));
    };

    // Q fragments: rows 0-15 (a) and 16-31 (b); Q pre-scaled by 1/8
    bf16x8 qa0 = *(const bf16x8*)&qbase[(size_t)fr * DH + kg * 8];
    bf16x8 qa1 = *(const bf16x8*)&qbase[(size_t)fr * DH + 32 + kg * 8];
    bf16x8 qb0 = *(const bf16x8*)&qbase[(size_t)(16 + fr) * DH + kg * 8];
    bf16x8 qb1 = *(const bf16x8*)&qbase[(size_t)(16 + fr) * DH + 32 + kg * 8];

    // ---- QK^T + masked exp fused into scatter; wave covers s in [wave*128,+128) ----
    {
      int sw = wave * 128;
      bf16x8 kb0[8], kb1[8];
      auto kload = [&](int g) {
        const bf16* kp = kbase + (size_t)(sw + g * 16 + fr) * DH + kg * 8;
        kb0[g & 7] = *(const bf16x8*)kp;
        kb1[g & 7] = *(const bf16x8*)(kp + 32);
      };
#pragma unroll
      for (int g = 0; g < 4; ++g) kload(g);
#pragma unroll
      for (int g = 0; g < 8; ++g) {
        if (g < 4) kload(g + 4);
        f32x4 aa = {0.f, 0.f, 0.f, 0.f};
        f32x4 ab = {0.f, 0.f, 0.f, 0.f};
        aa = mfma16(qa0, kb0[g & 7], aa);
        aa = mfma16(qa1, kb1[g & 7], aa);
        ab = mfma16(qb0, kb0[g & 7], ab);
        ab = mfma16(qb1, kb1[g & 7], ab);
        int col = sw + g * 16 + fr;
        unsigned int bits = mTb[col];
        int slot = col >> 3, within = col & 7;
#pragma unroll
        for (int j = 0; j < 4; ++j) {
          int ra = kg * 4 + j;
          int rb_ = ra + 16;
          float fa = ((bits >> ra) & 1u) ? __expf(aa[j]) : 0.f;
          float fb = ((bits >> rb_) & 1u) ? __expf(ab[j]) : 0.f;
          *(bf16*)(smem + ra * 4096 + ((slot ^ ra) << 4) + within * 2) =
              (bf16)fa;
          *(bf16*)(smem + rb_ * 4096 + ((slot ^ rb_) << 4) + within * 2) =
              (bf16)fb;
        }
      }
    }
    __syncthreads();

    // ---- early V prefetch (global, independent of LDS state) ----
    vbload(0);
    vbload(1);
    vbload(2);
    vbload(3);

    // ---- row-sum (probs already masked+exp'd in LDS) ----
    {
      int row = wave * 2 + (lane >> 5);
      int la = lane & 31;
      char* rbase = smem + row * 4096;
      float sum = 0.f;
#pragma unroll
      for (int it = 0; it < 8; ++it) {
        int slot = la + it * 32;
        bf16x8 e = *(const bf16x8*)(rbase + ((slot ^ row) << 4));
#pragma unroll
        for (int i = 0; i < 8; ++i) sum += (float)e[i];
      }
#pragma unroll
      for (int off = 1; off < 32; off <<= 1) sum += __shfl_xor(sum, off);
      if (la == 0) invp[row] = 1.f / sum;
    }
    __syncthreads();

    // ---- PV: wave = (rb, dq, kh2); V prefetched 4 deep; setprio on MFMAs ----
    {
      f32x4 cacc = {0.f, 0.f, 0.f, 0.f};
      pbload(0);
      pbload(1);
      pbload(2);
      pbload(3);
      __builtin_amdgcn_s_setprio(1);
#pragma unroll
      for (int kk = 0; kk < 32; ++kk) {
        if (kk < 28) {
          vbload(kk + 4);
          pbload(kk + 4);
        }
        cacc = mfma16(pb[kk & 7], vb[kk & 7], cacc);
      }
      __builtin_amdgcn_s_setprio(0);
      if (kh2 == 1) {
#pragma unroll
        for (int j = 0; j < 4; ++j)
          pbuf[((rb * 4 + dq) * 16 + kg * 4 + j) * 16 + fr] = cacc[j];
      }
      __syncthreads();
      if (kh2 == 0) {
#pragma unroll
        for (int j = 0; j < 4; ++j) {
          int row = rb * 16 + kg * 4 + j;
          float v =
              (cacc[j] + pbuf[((rb * 4 + dq) * 16 + kg * 4 + j) * 16 + fr]) *
              invp[row];
          ctx[((size_t)b * SS + q0 + row) * DM + h * DH + dq * 16 + fr] =
              (bf16)v;
        }
      }
    }

    // ---- prob store: issue, then (next sub-tile's compute) overlaps drain ----
    {
      int t = tid & 511, rh = tid >> 9;
      int slot = t >> 1, halfoff = (t & 1) * 8;
      float* outb = attn_out + ((size_t)bh * SS + q0) * SS;
#pragma unroll
      for (int it = 0; it < 16; ++it) {
        int r = it * 2 + rh;
        bf16x4 e =
            *(const bf16x4*)(smem + r * 4096 + ((slot ^ r) << 4) + halfoff);
        float inv = invp[r];
        f32x4 u = {(float)e[0] * inv, (float)e[1] * inv, (float)e[2] * inv,
                   (float)e[3] * inv};
        *(f32x4*)(outb + (size_t)r * SS + t * 4) = u;
      }
    }
    // LDS reads of the store phase must retire before next sub-tile's scatter;
    // global stores keep draining asynchronously under the next QK^T/PV.
    __syncthreads();
  }
}

// ---------------- LayerNorm (in-place on y region) ----------------
__global__ __launch_bounds__(256) void ln_k(float* __restrict__ x,
                                            const float* __restrict__ g,
                                            const float* __restrict__ bln) {
  int r = blockIdx.x, tid = threadIdx.x;
  f32x4 v = *(const f32x4*)&x[(size_t)r * DM + tid * 4];
  float s = v[0] + v[1] + v[2] + v[3];
  float s2 = v[0] * v[0] + v[1] * v[1] + v[2] * v[2] + v[3] * v[3];
#pragma unroll
  for (int off = 32; off; off >>= 1) {
    s += __shfl_down(s, off);
    s2 += __shfl_down(s2, off);
  }
  __shared__ float rs_[4], rs2_[4];
  int wave = tid >> 6, lane = tid & 63;
  if (lane == 0) {
    rs_[wave] = s;
    rs2_[wave] = s2;
  }
  __syncthreads();
  s = rs_[0] + rs_[1] + rs_[2] + rs_[3];
  s2 = rs2_[0] + rs2_[1] + rs2_[2] + rs2_[3];
  float mu = s * (1.f / DM);
  float var = s2 * (1.f / DM) - mu * mu;
  float rstd = rsqrtf(var + 1e-5f);
  f32x4 gg = *(const f32x4*)&g[tid * 4];
  f32x4 bb = *(const f32x4*)&bln[tid * 4];
  f32x4 o;
#pragma unroll
  for (int i = 0; i < 4; ++i) o[i] = (v[i] - mu) * rstd * gg[i] + bb[i];
  *(f32x4*)&x[(size_t)r * DM + tid * 4] = o;
}

extern "C" void kernel_launch(void* const* d_in, const int* in_sizes, int n_in,
                              void* d_out, int out_size, void* d_ws,
                              size_t ws_size, hipStream_t stream) {
  const float* q = (const float*)d_in[0];
  const float* k = (const float*)d_in[1];
  const float* v = (const float*)d_in[2];
  const int* mask = (const int*)d_in[3];
  const float* w_q = (const float*)d_in[4];
  const float* b_q = (const float*)d_in[5];
  const float* w_k = (const float*)d_in[6];
  const float* b_k = (const float*)d_in[7];
  const float* w_v = (const float*)d_in[8];
  const float* b_v = (const float*)d_in[9];
  const float* w_fc = (const float*)d_in[10];
  const float* b_fc = (const float*)d_in[11];
  const float* ln_g = (const float*)d_in[12];
  const float* ln_b = (const float*)d_in[13];

  float* y = (float*)d_out;                           // [8192][1024] fp32
  float* attn_out = (float*)d_out + (size_t)MM * DM;  // [64][2048][2048] fp32

  char* w = (char*)d_ws;
  const size_t actN = (size_t)MM * DM;  // 8388608
  bf16* qkv_bf = (bf16*)w;  w += 3 * actN * 2;            // q,k,v bf16
  bf16* wT = (bf16*)w;      w += (size_t)4 * DM * DM * 2; // wq,wk,wv,wfc ^T
  bf16* qhh = (bf16*)w;     w += actN * 2;
  bf16* khh = (bf16*)w;     w += actN * 2;
  bf16* vhT = (bf16*)w;     w += actN * 2;
  bf16* ctx = (bf16*)w;     w += actN * 2;
  unsigned int* mT = (unsigned int*)w;  w += (size_t)BB * 64 * SS * 4;

  // 0. transposed mask bitmask (2 MB, L2-resident)
  mask_bitsT<<<dim3(SS / 32, BB), 256, 0, stream>>>(mask, mT);
  // 1. convert activations
  cvt3<<<dim3(4096, 3), 256, 0, stream>>>(q, k, v, qkv_bf);
  // 2. transpose+convert all 4 weights
  wtrans4<<<dim3(DM / 32, DM / 32, 4), 256, 0, stream>>>(w_q, w_k, w_v, w_fc, wT);
  // 3. fused QKV projection (Q pre-scaled, V tiled-transposed)
  gemm_qkv<<<dim3(MM / 128, 3072 / 128), 256, 0, stream>>>(
      qkv_bf, wT, b_q, b_k, b_v, qhh, khh, vhT);
  // 4. fused attention: 2 q-tiles/block, in-block store/compute overlap
  hipFuncSetAttribute((const void*)attn_kernel,
                      hipFuncAttributeMaxDynamicSharedMemorySize, 139392);
  attn_kernel<<<2048, 1024, 139392, stream>>>(
      qhh, khh, vhT, mT, attn_out, ctx);
  // 5. output projection + bias + residual
  gemm_out<<<dim3(MM / 128, DM / 128), 256, 0, stream>>>(
      ctx, wT + (size_t)3 * DM * DM, b_fc, q, y);
  // 6. LayerNorm in place
  ln_k<<<MM, 256, 0, stream>>>(y, ln_g, ln_b);
}

// Round 17
// 653.733 us; speedup vs baseline: 3.8539x; 3.8539x over previous
//
#include <hip/hip_runtime.h>
#include <cstdint>
#include <cstddef>

#define DM 1024
#define HN 16
#define DH 64
#define BB 4
#define SS 2048
#define MM (BB * SS)  // 8192

typedef __bf16 bf16;
typedef bf16 bf16x8 __attribute__((ext_vector_type(8)));
typedef bf16 bf16x4 __attribute__((ext_vector_type(4)));
typedef float f32x4 __attribute__((ext_vector_type(4)));
typedef int i32x4 __attribute__((ext_vector_type(4)));

__device__ __forceinline__ f32x4 mfma16(bf16x8 a, bf16x8 b, f32x4 c) {
  return __builtin_amdgcn_mfma_f32_16x16x32_bf16(a, b, c, 0, 0, 0);
}

typedef __attribute__((address_space(3))) void lds_void_t;
typedef __attribute__((address_space(1))) void glob_void_t;

__device__ __forceinline__ void gload16(const void* g, void* l) {
  __builtin_amdgcn_global_load_lds((const glob_void_t*)g, (lds_void_t*)l, 16, 0, 0);
}

// ------- transposed mask bitmask: mT[b][qt][col] bit r = mask[b][qt*32+r][col] -------
__global__ __launch_bounds__(256) void mask_bitsT(const int* __restrict__ mask,
                                                  unsigned int* __restrict__ mT) {
  int qt = blockIdx.x, b = blockIdx.y;
  int col0 = threadIdx.x * 8;
  unsigned int m[8] = {0, 0, 0, 0, 0, 0, 0, 0};
  const int* mp = mask + ((size_t)b * SS + qt * 32) * SS + col0;
  for (int r = 0; r < 32; ++r) {
    i32x4 a = *(const i32x4*)(mp + (size_t)r * SS);
    i32x4 c = *(const i32x4*)(mp + (size_t)r * SS + 4);
#pragma unroll
    for (int i = 0; i < 4; ++i) {
      m[i] |= (unsigned int)(a[i] != 0) << r;
      m[4 + i] |= (unsigned int)(c[i] != 0) << r;
    }
  }
#pragma unroll
  for (int i = 0; i < 8; ++i)
    mT[((size_t)b * 64 + qt) * SS + col0 + i] = m[i];
}

// ---------------- fp32 -> bf16 convert, 3 tensors in one launch ----------------
__global__ __launch_bounds__(256) void cvt3(const float* __restrict__ q,
                                            const float* __restrict__ k,
                                            const float* __restrict__ v,
                                            bf16* __restrict__ dst) {
  int which = blockIdx.y;
  const float* in = which == 0 ? q : which == 1 ? k : v;
  bf16* out = dst + (size_t)which * MM * DM;
  int i = (blockIdx.x * 256 + threadIdx.x) * 8;
  f32x4 a = *(const f32x4*)(in + i);
  f32x4 b = *(const f32x4*)(in + i + 4);
  bf16x8 o;
  o[0] = (bf16)a[0]; o[1] = (bf16)a[1]; o[2] = (bf16)a[2]; o[3] = (bf16)a[3];
  o[4] = (bf16)b[0]; o[5] = (bf16)b[1]; o[6] = (bf16)b[2]; o[7] = (bf16)b[3];
  *(bf16x8*)(out + i) = o;
}

// ------------- weight transpose+convert, 4 weights: WT[p*1024+n][k] = Wp[k][n] -------------
__global__ __launch_bounds__(256) void wtrans4(const float* __restrict__ w_q,
                                               const float* __restrict__ w_k,
                                               const float* __restrict__ w_v,
                                               const float* __restrict__ w_fc,
                                               bf16* __restrict__ WT) {
  int p = blockIdx.z;
  const float* W = p == 0 ? w_q : p == 1 ? w_k : p == 2 ? w_v : w_fc;
  bf16* out = WT + (size_t)p * DM * DM;
  __shared__ float t[32][33];
  int n0 = blockIdx.x * 32, k0 = blockIdx.y * 32;
  int tid = threadIdx.x;
  int r = tid >> 3, c = (tid & 7) * 4;
  f32x4 v = *(const f32x4*)&W[(size_t)(k0 + r) * DM + n0 + c];
  t[r][c] = v[0]; t[r][c + 1] = v[1]; t[r][c + 2] = v[2]; t[r][c + 3] = v[3];
  __syncthreads();
  bf16x4 o;
#pragma unroll
  for (int i = 0; i < 4; ++i) o[i] = (bf16)t[c + i][r];
  *(bf16x4*)&out[(size_t)(n0 + r) * DM + k0 + c] = o;
}

// ---------------- fused QKV projection GEMM (N=3072) ----------------
// proj 0 (Q): head layout [bh][s][d], *0.125
// proj 1 (K): head layout [bh][s][d]
// proj 2 (V): TILED transposed layout [bh][s/32][d][s%32]
__global__ __launch_bounds__(256) void gemm_qkv(const bf16* __restrict__ Abase,
                                                const bf16* __restrict__ Bt,
                                                const float* __restrict__ b_q,
                                                const float* __restrict__ b_k,
                                                const float* __restrict__ b_v,
                                                bf16* __restrict__ qhh,
                                                bf16* __restrict__ khh,
                                                bf16* __restrict__ vhT) {
  constexpr int K = DM;
  __shared__ bf16 Ab[128 * 32];
  __shared__ bf16 Bb[128 * 32];
  int tid = threadIdx.x, wave = tid >> 6, lane = tid & 63;
  int bm = blockIdx.x * 128, bn = blockIdx.y * 128;
  int proj = bn >> 10;
  const bf16* A = Abase + (size_t)proj * MM * DM;
  const float* bias = proj == 0 ? b_q : proj == 1 ? b_k : b_v;
  int wr = (wave >> 1) * 64, wc = (wave & 1) * 64;
  int fr = lane & 15, kg8 = (lane >> 4) * 8;
  f32x4 acc[4][4] = {};
  int arow = tid >> 2, acol = (tid & 3) * 8;
  const bf16* Ag0 = A + (size_t)(bm + arow) * K + acol;
  const bf16* Ag1 = Ag0 + (size_t)64 * K;
  const bf16* Bg0 = Bt + (size_t)(bn + arow) * K + acol;
  const bf16* Bg1 = Bg0 + (size_t)64 * K;
  char* la = (char*)Ab + wave * 1024;
  char* lb = (char*)Bb + wave * 1024;
  for (int k0 = 0; k0 < K; k0 += 32) {
    __syncthreads();
    gload16(Ag0 + k0, la);
    gload16(Ag1 + k0, la + 4096);
    gload16(Bg0 + k0, lb);
    gload16(Bg1 + k0, lb + 4096);
    asm volatile("s_waitcnt vmcnt(0)" ::: "memory");
    __syncthreads();
    bf16x8 af[4], bfr[4];
#pragma unroll
    for (int m = 0; m < 4; ++m)
      af[m] = *(const bf16x8*)&Ab[(wr + m * 16 + fr) * 32 + kg8];
#pragma unroll
    for (int n = 0; n < 4; ++n)
      bfr[n] = *(const bf16x8*)&Bb[(wc + n * 16 + fr) * 32 + kg8];
#pragma unroll
    for (int m = 0; m < 4; ++m)
#pragma unroll
      for (int n = 0; n < 4; ++n) acc[m][n] = mfma16(af[m], bfr[n], acc[m][n]);
  }
  int b = bm >> 11;
#pragma unroll
  for (int m = 0; m < 4; ++m)
#pragma unroll
    for (int n = 0; n < 4; ++n) {
      int c = bn + wc + n * 16 + fr;
      int lc = c & 1023;
      float bv = bias[lc];
      int h = lc >> 6, d = lc & 63;
      int r0 = bm + wr + m * 16 + (lane >> 4) * 4;
      int s0 = r0 & (SS - 1);
      if (proj == 2) {
        bf16x4 o;
#pragma unroll
        for (int j = 0; j < 4; ++j) o[j] = (bf16)(acc[m][n][j] + bv);
        *(bf16x4*)&vhT[(size_t)(b * HN + h) * (SS * DH) +
                       (size_t)(s0 >> 5) * (DH * 32) + d * 32 + (s0 & 31)] = o;
      } else {
        bf16* dst = proj == 0 ? qhh : khh;
        float sc = proj == 0 ? 0.125f : 1.f;
#pragma unroll
        for (int j = 0; j < 4; ++j) {
          float v = (acc[m][n][j] + bv) * sc;
          dst[(size_t)(b * HN + h) * (SS * DH) + (size_t)(s0 + j) * DH + d] =
              (bf16)v;
        }
      }
    }
}

// ---------------- out-proj GEMM: fp32 out + bias + residual ----------------
__global__ __launch_bounds__(256) void gemm_out(const bf16* __restrict__ A,
                                                const bf16* __restrict__ Bt,
                                                const float* __restrict__ bias,
                                                const float* __restrict__ resid,
                                                float* __restrict__ out) {
  constexpr int K = DM;
  __shared__ bf16 Ab[128 * 32];
  __shared__ bf16 Bb[128 * 32];
  int tid = threadIdx.x, wave = tid >> 6, lane = tid & 63;
  int bm = blockIdx.x * 128, bn = blockIdx.y * 128;
  int wr = (wave >> 1) * 64, wc = (wave & 1) * 64;
  int fr = lane & 15, kg8 = (lane >> 4) * 8;
  f32x4 acc[4][4] = {};
  int arow = tid >> 2, acol = (tid & 3) * 8;
  const bf16* Ag0 = A + (size_t)(bm + arow) * K + acol;
  const bf16* Ag1 = Ag0 + (size_t)64 * K;
  const bf16* Bg0 = Bt + (size_t)(bn + arow) * K + acol;
  const bf16* Bg1 = Bg0 + (size_t)64 * K;
  char* la = (char*)Ab + wave * 1024;
  char* lb = (char*)Bb + wave * 1024;
  for (int k0 = 0; k0 < K; k0 += 32) {
    __syncthreads();
    gload16(Ag0 + k0, la);
    gload16(Ag1 + k0, la + 4096);
    gload16(Bg0 + k0, lb);
    gload16(Bg1 + k0, lb + 4096);
    asm volatile("s_waitcnt vmcnt(0)" ::: "memory");
    __syncthreads();
    bf16x8 af[4], bfr[4];
#pragma unroll
    for (int m = 0; m < 4; ++m)
      af[m] = *(const bf16x8*)&Ab[(wr + m * 16 + fr) * 32 + kg8];
#pragma unroll
    for (int n = 0; n < 4; ++n)
      bfr[n] = *(const bf16x8*)&Bb[(wc + n * 16 + fr) * 32 + kg8];
#pragma unroll
    for (int m = 0; m < 4; ++m)
#pragma unroll
      for (int n = 0; n < 4; ++n) acc[m][n] = mfma16(af[m], bfr[n], acc[m][n]);
  }
#pragma unroll
  for (int m = 0; m < 4; ++m)
#pragma unroll
    for (int n = 0; n < 4; ++n) {
      int c = bn + wc + n * 16 + fr;
      float bv = bias[c];
#pragma unroll
      for (int j = 0; j < 4; ++j) {
        int r = bm + wr + m * 16 + (lane >> 4) * 4 + j;
        size_t idx = (size_t)r * DM + c;
        out[idx] = acc[m][n][j] + bv + resid[idx];
      }
    }
}

// ---------------- fused attention: QBLK=32, 1024 threads, store-last ----------------
// grid: 4096 blocks 1D (XCD-swizzled). LDS: 32*4096 probs + 8192 pbuf + 128 invp
// R11 structure + (a) early V prefetch before rowsum, (b) setprio around PV MFMAs.
__global__ __launch_bounds__(1024, 4) void attn_kernel(
    const bf16* __restrict__ qh, const bf16* __restrict__ kh,
    const bf16* __restrict__ vhT, const unsigned int* __restrict__ mT,
    float* __restrict__ attn_out, bf16* __restrict__ ctx) {
  extern __shared__ char smem[];
  float* pbuf = (float*)(smem + 32 * 4096);
  float* invp = (float*)(smem + 32 * 4096 + 8192);
  int tid = threadIdx.x, wave = tid >> 6, lane = tid & 63;
  // XCD-aware bijective swizzle: 4096 = 8 XCDs x 512; consecutive fids share bh
  int fid = (blockIdx.x & 7) * 512 + (blockIdx.x >> 3);
  int bh = fid >> 6, qt = fid & 63;
  int b = bh >> 4, h = bh & 15;
  int q0 = qt * 32;
  const bf16* qbase = qh + ((size_t)bh * SS + q0) * DH;
  const bf16* kbase = kh + (size_t)bh * SS * DH;
  const bf16* vbase = vhT + (size_t)bh * SS * DH;  // tiled [s/32][64][32]
  const unsigned int* mTb = mT + ((size_t)b * 64 + qt) * SS;
  int fr = lane & 15, kg = lane >> 4;

  // PV wave decomposition (computed early for V prefetch)
  int rb = wave >> 3, dq = (wave >> 1) & 3, kh2 = wave & 1;
  const bf16* vtile = vbase + (size_t)(kh2 * 32) * (DH * 32) +
                      (dq * 16 + fr) * 32 + kg * 8;
  int prow_row = rb * 16 + fr;
  char* prow = smem + prow_row * 4096;
  bf16x8 vb[8], pb[8];
  auto vbload = [&](int kk) {
    vb[kk & 7] = *(const bf16x8*)&vtile[(size_t)kk * (DH * 32)];
  };
  auto pbload = [&](int kk) {
    int slotA = kh2 * 128 + kk * 4 + kg;
    pb[kk & 7] = *(const bf16x8*)(prow + ((slotA ^ prow_row) << 4));
  };

  // Q fragments: rows 0-15 (a) and 16-31 (b); Q pre-scaled by 1/8
  bf16x8 qa0 = *(const bf16x8*)&qbase[(size_t)fr * DH + kg * 8];
  bf16x8 qa1 = *(const bf16x8*)&qbase[(size_t)fr * DH + 32 + kg * 8];
  bf16x8 qb0 = *(const bf16x8*)&qbase[(size_t)(16 + fr) * DH + kg * 8];
  bf16x8 qb1 = *(const bf16x8*)&qbase[(size_t)(16 + fr) * DH + 32 + kg * 8];

  // ---- QK^T + masked exp fused into scatter; wave covers s in [wave*128,+128) ----
  {
    int sw = wave * 128;
    bf16x8 kb0[8], kb1[8];
    auto kload = [&](int g) {
      const bf16* kp = kbase + (size_t)(sw + g * 16 + fr) * DH + kg * 8;
      kb0[g & 7] = *(const bf16x8*)kp;
      kb1[g & 7] = *(const bf16x8*)(kp + 32);
    };
#pragma unroll
    for (int g = 0; g < 4; ++g) kload(g);
#pragma unroll
    for (int g = 0; g < 8; ++g) {
      if (g < 4) kload(g + 4);
      f32x4 aa = {0.f, 0.f, 0.f, 0.f};
      f32x4 ab = {0.f, 0.f, 0.f, 0.f};
      aa = mfma16(qa0, kb0[g & 7], aa);
      aa = mfma16(qa1, kb1[g & 7], aa);
      ab = mfma16(qb0, kb0[g & 7], ab);
      ab = mfma16(qb1, kb1[g & 7], ab);
      int col = sw + g * 16 + fr;
      unsigned int bits = mTb[col];
      int slot = col >> 3, within = col & 7;
#pragma unroll
      for (int j = 0; j < 4; ++j) {
        int ra = kg * 4 + j;
        int rb_ = ra + 16;
        float fa = ((bits >> ra) & 1u) ? __expf(aa[j]) : 0.f;
        float fb = ((bits >> rb_) & 1u) ? __expf(ab[j]) : 0.f;
        *(bf16*)(smem + ra * 4096 + ((slot ^ ra) << 4) + within * 2) = (bf16)fa;
        *(bf16*)(smem + rb_ * 4096 + ((slot ^ rb_) << 4) + within * 2) = (bf16)fb;
      }
    }
  }
  __syncthreads();

  // ---- early V prefetch (global, independent of LDS state) ----
  vbload(0);
  vbload(1);
  vbload(2);
  vbload(3);

  // ---- row-sum (probs already masked+exp'd in LDS) ----
  {
    int row = wave * 2 + (lane >> 5);
    int la = lane & 31;
    char* rbase = smem + row * 4096;
    float sum = 0.f;
#pragma unroll
    for (int it = 0; it < 8; ++it) {
      int slot = la + it * 32;
      bf16x8 e = *(const bf16x8*)(rbase + ((slot ^ row) << 4));
#pragma unroll
      for (int i = 0; i < 8; ++i) sum += (float)e[i];
    }
#pragma unroll
    for (int off = 1; off < 32; off <<= 1) sum += __shfl_xor(sum, off);
    if (la == 0) invp[row] = 1.f / sum;
  }
  __syncthreads();

  // ---- PV: wave = (rb, dq, kh2); V already prefetched 4 deep ----
  {
    f32x4 cacc = {0.f, 0.f, 0.f, 0.f};
    pbload(0);
    pbload(1);
    pbload(2);
    pbload(3);
    __builtin_amdgcn_s_setprio(1);
#pragma unroll
    for (int kk = 0; kk < 32; ++kk) {
      if (kk < 28) {
        vbload(kk + 4);
        pbload(kk + 4);
      }
      cacc = mfma16(pb[kk & 7], vb[kk & 7], cacc);
    }
    __builtin_amdgcn_s_setprio(0);
    if (kh2 == 1) {
#pragma unroll
      for (int j = 0; j < 4; ++j)
        pbuf[((rb * 4 + dq) * 16 + kg * 4 + j) * 16 + fr] = cacc[j];
    }
    __syncthreads();
    if (kh2 == 0) {
#pragma unroll
      for (int j = 0; j < 4; ++j) {
        int row = rb * 16 + kg * 4 + j;
        float v = (cacc[j] + pbuf[((rb * 4 + dq) * 16 + kg * 4 + j) * 16 + fr]) *
                  invp[row];
        ctx[((size_t)b * SS + q0 + row) * DM + h * DH + dq * 16 + fr] = (bf16)v;
      }
    }
  }

  // ---- prob store LAST: fire-and-forget, drains past endpgm ----
  {
    int t = tid & 511, rh = tid >> 9;
    int slot = t >> 1, halfoff = (t & 1) * 8;
    float* outb = attn_out + ((size_t)bh * SS + q0) * SS;
#pragma unroll
    for (int it = 0; it < 16; ++it) {
      int r = it * 2 + rh;
      bf16x4 e = *(const bf16x4*)(smem + r * 4096 + ((slot ^ r) << 4) + halfoff);
      float inv = invp[r];
      f32x4 u = {(float)e[0] * inv, (float)e[1] * inv, (float)e[2] * inv,
                 (float)e[3] * inv};
      *(f32x4*)(outb + (size_t)r * SS + t * 4) = u;
    }
  }
}

// ---------------- LayerNorm (in-place on y region) ----------------
__global__ __launch_bounds__(256) void ln_k(float* __restrict__ x,
                                            const float* __restrict__ g,
                                            const float* __restrict__ bln) {
  int r = blockIdx.x, tid = threadIdx.x;
  f32x4 v = *(const f32x4*)&x[(size_t)r * DM + tid * 4];
  float s = v[0] + v[1] + v[2] + v[3];
  float s2 = v[0] * v[0] + v[1] * v[1] + v[2] * v[2] + v[3] * v[3];
#pragma unroll
  for (int off = 32; off; off >>= 1) {
    s += __shfl_down(s, off);
    s2 += __shfl_down(s2, off);
  }
  __shared__ float rs_[4], rs2_[4];
  int wave = tid >> 6, lane = tid & 63;
  if (lane == 0) {
    rs_[wave] = s;
    rs2_[wave] = s2;
  }
  __syncthreads();
  s = rs_[0] + rs_[1] + rs_[2] + rs_[3];
  s2 = rs2_[0] + rs2_[1] + rs2_[2] + rs2_[3];
  float mu = s * (1.f / DM);
  float var = s2 * (1.f / DM) - mu * mu;
  float rstd = rsqrtf(var + 1e-5f);
  f32x4 gg = *(const f32x4*)&g[tid * 4];
  f32x4 bb = *(const f32x4*)&bln[tid * 4];
  f32x4 o;
#pragma unroll
  for (int i = 0; i < 4; ++i) o[i] = (v[i] - mu) * rstd * gg[i] + bb[i];
  *(f32x4*)&x[(size_t)r * DM + tid * 4] = o;
}

extern "C" void kernel_launch(void* const* d_in, const int* in_sizes, int n_in,
                              void* d_out, int out_size, void* d_ws,
                              size_t ws_size, hipStream_t stream) {
  const float* q = (const float*)d_in[0];
  const float* k = (const float*)d_in[1];
  const float* v = (const float*)d_in[2];
  const int* mask = (const int*)d_in[3];
  const float* w_q = (const float*)d_in[4];
  const float* b_q = (const float*)d_in[5];
  const float* w_k = (const float*)d_in[6];
  const float* b_k = (const float*)d_in[7];
  const float* w_v = (const float*)d_in[8];
  const float* b_v = (const float*)d_in[9];
  const float* w_fc = (const float*)d_in[10];
  const float* b_fc = (const float*)d_in[11];
  const float* ln_g = (const float*)d_in[12];
  const float* ln_b = (const float*)d_in[13];

  float* y = (float*)d_out;                           // [8192][1024] fp32
  float* attn_out = (float*)d_out + (size_t)MM * DM;  // [64][2048][2048] fp32

  char* w = (char*)d_ws;
  const size_t actN = (size_t)MM * DM;  // 8388608
  bf16* qkv_bf = (bf16*)w;  w += 3 * actN * 2;            // q,k,v bf16
  bf16* wT = (bf16*)w;      w += (size_t)4 * DM * DM * 2; // wq,wk,wv,wfc ^T
  bf16* qhh = (bf16*)w;     w += actN * 2;
  bf16* khh = (bf16*)w;     w += actN * 2;
  bf16* vhT = (bf16*)w;     w += actN * 2;
  bf16* ctx = (bf16*)w;     w += actN * 2;
  unsigned int* mT = (unsigned int*)w;  w += (size_t)BB * 64 * SS * 4;

  // 0. transposed mask bitmask (2 MB, L2-resident)
  mask_bitsT<<<dim3(SS / 32, BB), 256, 0, stream>>>(mask, mT);
  // 1. convert activations
  cvt3<<<dim3(4096, 3), 256, 0, stream>>>(q, k, v, qkv_bf);
  // 2. transpose+convert all 4 weights
  wtrans4<<<dim3(DM / 32, DM / 32, 4), 256, 0, stream>>>(w_q, w_k, w_v, w_fc, wT);
  // 3. fused QKV projection (Q pre-scaled, V tiled-transposed)
  gemm_qkv<<<dim3(MM / 128, 3072 / 128), 256, 0, stream>>>(
      qkv_bf, wT, b_q, b_k, b_v, qhh, khh, vhT);
  // 4. fused attention: QBLK=32, 1024 threads, XCD-swizzled, store-last
  hipFuncSetAttribute((const void*)attn_kernel,
                      hipFuncAttributeMaxDynamicSharedMemorySize, 139392);
  attn_kernel<<<4096, 1024, 139392, stream>>>(
      qhh, khh, vhT, mT, attn_out, ctx);
  // 5. output projection + bias + residual
  gemm_out<<<dim3(MM / 128, DM / 128), 256, 0, stream>>>(
      ctx, wT + (size_t)3 * DM * DM, b_fc, q, y);
  // 6. LayerNorm in place
  ln_k<<<MM, 256, 0, stream>>>(y, ln_g, ln_b);
}

// Round 18
// 643.971 us; speedup vs baseline: 3.9123x; 1.0152x over previous
//
#include <hip/hip_runtime.h>
#include <cstdint>
#include <cstddef>

#define DM 1024
#define HN 16
#define DH 64
#define BB 4
#define SS 2048
#define MM (BB * SS)  // 8192

typedef __bf16 bf16;
typedef bf16 bf16x8 __attribute__((ext_vector_type(8)));
typedef bf16 bf16x4 __attribute__((ext_vector_type(4)));
typedef float f32x4 __attribute__((ext_vector_type(4)));
typedef int i32x4 __attribute__((ext_vector_type(4)));

__device__ __forceinline__ f32x4 mfma16(bf16x8 a, bf16x8 b, f32x4 c) {
  return __builtin_amdgcn_mfma_f32_16x16x32_bf16(a, b, c, 0, 0, 0);
}

typedef __attribute__((address_space(3))) void lds_void_t;
typedef __attribute__((address_space(1))) void glob_void_t;

__device__ __forceinline__ void gload16(const void* g, void* l) {
  __builtin_amdgcn_global_load_lds((const glob_void_t*)g, (lds_void_t*)l, 16, 0, 0);
}

// ------- transposed mask bitmask: mT[b][qt][col] bit r = mask[b][qt*32+r][col] -------
__global__ __launch_bounds__(256) void mask_bitsT(const int* __restrict__ mask,
                                                  unsigned int* __restrict__ mT) {
  int qt = blockIdx.x, b = blockIdx.y;
  int col0 = threadIdx.x * 8;
  unsigned int m[8] = {0, 0, 0, 0, 0, 0, 0, 0};
  const int* mp = mask + ((size_t)b * SS + qt * 32) * SS + col0;
  for (int r = 0; r < 32; ++r) {
    i32x4 a = *(const i32x4*)(mp + (size_t)r * SS);
    i32x4 c = *(const i32x4*)(mp + (size_t)r * SS + 4);
#pragma unroll
    for (int i = 0; i < 4; ++i) {
      m[i] |= (unsigned int)(a[i] != 0) << r;
      m[4 + i] |= (unsigned int)(c[i] != 0) << r;
    }
  }
#pragma unroll
  for (int i = 0; i < 8; ++i)
    mT[((size_t)b * 64 + qt) * SS + col0 + i] = m[i];
}

// ---------------- fp32 -> bf16 convert, 3 tensors in one launch ----------------
__global__ __launch_bounds__(256) void cvt3(const float* __restrict__ q,
                                            const float* __restrict__ k,
                                            const float* __restrict__ v,
                                            bf16* __restrict__ dst) {
  int which = blockIdx.y;
  const float* in = which == 0 ? q : which == 1 ? k : v;
  bf16* out = dst + (size_t)which * MM * DM;
  int i = (blockIdx.x * 256 + threadIdx.x) * 8;
  f32x4 a = *(const f32x4*)(in + i);
  f32x4 b = *(const f32x4*)(in + i + 4);
  bf16x8 o;
  o[0] = (bf16)a[0]; o[1] = (bf16)a[1]; o[2] = (bf16)a[2]; o[3] = (bf16)a[3];
  o[4] = (bf16)b[0]; o[5] = (bf16)b[1]; o[6] = (bf16)b[2]; o[7] = (bf16)b[3];
  *(bf16x8*)(out + i) = o;
}

// ------------- weight transpose+convert, 4 weights: WT[p*1024+n][k] = Wp[k][n] -------------
__global__ __launch_bounds__(256) void wtrans4(const float* __restrict__ w_q,
                                               const float* __restrict__ w_k,
                                               const float* __restrict__ w_v,
                                               const float* __restrict__ w_fc,
                                               bf16* __restrict__ WT) {
  int p = blockIdx.z;
  const float* W = p == 0 ? w_q : p == 1 ? w_k : p == 2 ? w_v : w_fc;
  bf16* out = WT + (size_t)p * DM * DM;
  __shared__ float t[32][33];
  int n0 = blockIdx.x * 32, k0 = blockIdx.y * 32;
  int tid = threadIdx.x;
  int r = tid >> 3, c = (tid & 7) * 4;
  f32x4 v = *(const f32x4*)&W[(size_t)(k0 + r) * DM + n0 + c];
  t[r][c] = v[0]; t[r][c + 1] = v[1]; t[r][c + 2] = v[2]; t[r][c + 3] = v[3];
  __syncthreads();
  bf16x4 o;
#pragma unroll
  for (int i = 0; i < 4; ++i) o[i] = (bf16)t[c + i][r];
  *(bf16x4*)&out[(size_t)(n0 + r) * DM + k0 + c] = o;
}

// ---------------- fused QKV projection GEMM (N=3072) ----------------
// proj 0 (Q): head layout [bh][s][d], *0.125
// proj 1 (K): head layout [bh][s][d]
// proj 2 (V): TILED transposed layout [bh][s/32][d][s%32]
__global__ __launch_bounds__(256) void gemm_qkv(const bf16* __restrict__ Abase,
                                                const bf16* __restrict__ Bt,
                                                const float* __restrict__ b_q,
                                                const float* __restrict__ b_k,
                                                const float* __restrict__ b_v,
                                                bf16* __restrict__ qhh,
                                                bf16* __restrict__ khh,
                                                bf16* __restrict__ vhT) {
  constexpr int K = DM;
  __shared__ bf16 Ab[128 * 32];
  __shared__ bf16 Bb[128 * 32];
  int tid = threadIdx.x, wave = tid >> 6, lane = tid & 63;
  int bm = blockIdx.x * 128, bn = blockIdx.y * 128;
  int proj = bn >> 10;
  const bf16* A = Abase + (size_t)proj * MM * DM;
  const float* bias = proj == 0 ? b_q : proj == 1 ? b_k : b_v;
  int wr = (wave >> 1) * 64, wc = (wave & 1) * 64;
  int fr = lane & 15, kg8 = (lane >> 4) * 8;
  f32x4 acc[4][4] = {};
  int arow = tid >> 2, acol = (tid & 3) * 8;
  const bf16* Ag0 = A + (size_t)(bm + arow) * K + acol;
  const bf16* Ag1 = Ag0 + (size_t)64 * K;
  const bf16* Bg0 = Bt + (size_t)(bn + arow) * K + acol;
  const bf16* Bg1 = Bg0 + (size_t)64 * K;
  char* la = (char*)Ab + wave * 1024;
  char* lb = (char*)Bb + wave * 1024;
  for (int k0 = 0; k0 < K; k0 += 32) {
    __syncthreads();
    gload16(Ag0 + k0, la);
    gload16(Ag1 + k0, la + 4096);
    gload16(Bg0 + k0, lb);
    gload16(Bg1 + k0, lb + 4096);
    asm volatile("s_waitcnt vmcnt(0)" ::: "memory");
    __syncthreads();
    bf16x8 af[4], bfr[4];
#pragma unroll
    for (int m = 0; m < 4; ++m)
      af[m] = *(const bf16x8*)&Ab[(wr + m * 16 + fr) * 32 + kg8];
#pragma unroll
    for (int n = 0; n < 4; ++n)
      bfr[n] = *(const bf16x8*)&Bb[(wc + n * 16 + fr) * 32 + kg8];
#pragma unroll
    for (int m = 0; m < 4; ++m)
#pragma unroll
      for (int n = 0; n < 4; ++n) acc[m][n] = mfma16(af[m], bfr[n], acc[m][n]);
  }
  int b = bm >> 11;
#pragma unroll
  for (int m = 0; m < 4; ++m)
#pragma unroll
    for (int n = 0; n < 4; ++n) {
      int c = bn + wc + n * 16 + fr;
      int lc = c & 1023;
      float bv = bias[lc];
      int h = lc >> 6, d = lc & 63;
      int r0 = bm + wr + m * 16 + (lane >> 4) * 4;
      int s0 = r0 & (SS - 1);
      if (proj == 2) {
        bf16x4 o;
#pragma unroll
        for (int j = 0; j < 4; ++j) o[j] = (bf16)(acc[m][n][j] + bv);
        *(bf16x4*)&vhT[(size_t)(b * HN + h) * (SS * DH) +
                       (size_t)(s0 >> 5) * (DH * 32) + d * 32 + (s0 & 31)] = o;
      } else {
        bf16* dst = proj == 0 ? qhh : khh;
        float sc = proj == 0 ? 0.125f : 1.f;
#pragma unroll
        for (int j = 0; j < 4; ++j) {
          float v = (acc[m][n][j] + bv) * sc;
          dst[(size_t)(b * HN + h) * (SS * DH) + (size_t)(s0 + j) * DH + d] =
              (bf16)v;
        }
      }
    }
}

// ---------------- out-proj GEMM: fp32 out + bias + residual ----------------
__global__ __launch_bounds__(256) void gemm_out(const bf16* __restrict__ A,
                                                const bf16* __restrict__ Bt,
                                                const float* __restrict__ bias,
                                                const float* __restrict__ resid,
                                                float* __restrict__ out) {
  constexpr int K = DM;
  __shared__ bf16 Ab[128 * 32];
  __shared__ bf16 Bb[128 * 32];
  int tid = threadIdx.x, wave = tid >> 6, lane = tid & 63;
  int bm = blockIdx.x * 128, bn = blockIdx.y * 128;
  int wr = (wave >> 1) * 64, wc = (wave & 1) * 64;
  int fr = lane & 15, kg8 = (lane >> 4) * 8;
  f32x4 acc[4][4] = {};
  int arow = tid >> 2, acol = (tid & 3) * 8;
  const bf16* Ag0 = A + (size_t)(bm + arow) * K + acol;
  const bf16* Ag1 = Ag0 + (size_t)64 * K;
  const bf16* Bg0 = Bt + (size_t)(bn + arow) * K + acol;
  const bf16* Bg1 = Bg0 + (size_t)64 * K;
  char* la = (char*)Ab + wave * 1024;
  char* lb = (char*)Bb + wave * 1024;
  for (int k0 = 0; k0 < K; k0 += 32) {
    __syncthreads();
    gload16(Ag0 + k0, la);
    gload16(Ag1 + k0, la + 4096);
    gload16(Bg0 + k0, lb);
    gload16(Bg1 + k0, lb + 4096);
    asm volatile("s_waitcnt vmcnt(0)" ::: "memory");
    __syncthreads();
    bf16x8 af[4], bfr[4];
#pragma unroll
    for (int m = 0; m < 4; ++m)
      af[m] = *(const bf16x8*)&Ab[(wr + m * 16 + fr) * 32 + kg8];
#pragma unroll
    for (int n = 0; n < 4; ++n)
      bfr[n] = *(const bf16x8*)&Bb[(wc + n * 16 + fr) * 32 + kg8];
#pragma unroll
    for (int m = 0; m < 4; ++m)
#pragma unroll
      for (int n = 0; n < 4; ++n) acc[m][n] = mfma16(af[m], bfr[n], acc[m][n]);
  }
#pragma unroll
  for (int m = 0; m < 4; ++m)
#pragma unroll
    for (int n = 0; n < 4; ++n) {
      int c = bn + wc + n * 16 + fr;
      float bv = bias[c];
#pragma unroll
      for (int j = 0; j < 4; ++j) {
        int r = bm + wr + m * 16 + (lane >> 4) * 4 + j;
        size_t idx = (size_t)r * DM + c;
        out[idx] = acc[m][n][j] + bv + resid[idx];
      }
    }
}

// ---------------- fused attention: wave-specialized PV/store overlap ----------------
// grid: 4096 blocks 1D (XCD-swizzled), 1024 threads.
// LDS: 32*4096 probs + 128 invp (no pbuf: PV waves own full-k tiles).
// After rowsum barrier: waves 0-7 -> PV (full k=2048, 8 tiles) + ctx;
//                       waves 8-15 -> 256 KB prob store. Both read-only on LDS;
//                       no barrier between them -> store drain overlaps MFMA.
__global__ __launch_bounds__(1024, 4) void attn_kernel(
    const bf16* __restrict__ qh, const bf16* __restrict__ kh,
    const bf16* __restrict__ vhT, const unsigned int* __restrict__ mT,
    float* __restrict__ attn_out, bf16* __restrict__ ctx) {
  extern __shared__ char smem[];
  float* invp = (float*)(smem + 32 * 4096);
  int tid = threadIdx.x, wave = tid >> 6, lane = tid & 63;
  // XCD-aware bijective swizzle: 4096 = 8 XCDs x 512; consecutive fids share bh
  int fid = (blockIdx.x & 7) * 512 + (blockIdx.x >> 3);
  int bh = fid >> 6, qt = fid & 63;
  int b = bh >> 4, h = bh & 15;
  int q0 = qt * 32;
  const bf16* qbase = qh + ((size_t)bh * SS + q0) * DH;
  const bf16* kbase = kh + (size_t)bh * SS * DH;
  const bf16* vbase = vhT + (size_t)bh * SS * DH;  // tiled [s/32][64][32]
  const unsigned int* mTb = mT + ((size_t)b * 64 + qt) * SS;
  int fr = lane & 15, kg = lane >> 4;

  // Q fragments: rows 0-15 (a) and 16-31 (b); Q pre-scaled by 1/8
  bf16x8 qa0 = *(const bf16x8*)&qbase[(size_t)fr * DH + kg * 8];
  bf16x8 qa1 = *(const bf16x8*)&qbase[(size_t)fr * DH + 32 + kg * 8];
  bf16x8 qb0 = *(const bf16x8*)&qbase[(size_t)(16 + fr) * DH + kg * 8];
  bf16x8 qb1 = *(const bf16x8*)&qbase[(size_t)(16 + fr) * DH + 32 + kg * 8];

  // ---- QK^T + masked exp fused into scatter; wave covers s in [wave*128,+128) ----
  {
    int sw = wave * 128;
    bf16x8 kb0[8], kb1[8];
    auto kload = [&](int g) {
      const bf16* kp = kbase + (size_t)(sw + g * 16 + fr) * DH + kg * 8;
      kb0[g & 7] = *(const bf16x8*)kp;
      kb1[g & 7] = *(const bf16x8*)(kp + 32);
    };
#pragma unroll
    for (int g = 0; g < 4; ++g) kload(g);
#pragma unroll
    for (int g = 0; g < 8; ++g) {
      if (g < 4) kload(g + 4);
      f32x4 aa = {0.f, 0.f, 0.f, 0.f};
      f32x4 ab = {0.f, 0.f, 0.f, 0.f};
      aa = mfma16(qa0, kb0[g & 7], aa);
      aa = mfma16(qa1, kb1[g & 7], aa);
      ab = mfma16(qb0, kb0[g & 7], ab);
      ab = mfma16(qb1, kb1[g & 7], ab);
      int col = sw + g * 16 + fr;
      unsigned int bits = mTb[col];
      int slot = col >> 3, within = col & 7;
#pragma unroll
      for (int j = 0; j < 4; ++j) {
        int ra = kg * 4 + j;
        int rb_ = ra + 16;
        float fa = ((bits >> ra) & 1u) ? __expf(aa[j]) : 0.f;
        float fb = ((bits >> rb_) & 1u) ? __expf(ab[j]) : 0.f;
        *(bf16*)(smem + ra * 4096 + ((slot ^ ra) << 4) + within * 2) = (bf16)fa;
        *(bf16*)(smem + rb_ * 4096 + ((slot ^ rb_) << 4) + within * 2) = (bf16)fb;
      }
    }
  }
  __syncthreads();

  // ---- row-sum (all 16 waves; probs already masked+exp'd in LDS) ----
  {
    int row = wave * 2 + (lane >> 5);
    int la = lane & 31;
    char* rbase = smem + row * 4096;
    float sum = 0.f;
#pragma unroll
    for (int it = 0; it < 8; ++it) {
      int slot = la + it * 32;
      bf16x8 e = *(const bf16x8*)(rbase + ((slot ^ row) << 4));
#pragma unroll
      for (int i = 0; i < 8; ++i) sum += (float)e[i];
    }
#pragma unroll
    for (int off = 1; off < 32; off <<= 1) sum += __shfl_xor(sum, off);
    if (la == 0) invp[row] = 1.f / sum;
  }
  __syncthreads();

  // ---- wave split: 0-7 PV full-k; 8-15 prob store. No further barriers. ----
  if (wave < 8) {
    int rb = wave >> 2, dq = wave & 3;
    f32x4 cacc = {0.f, 0.f, 0.f, 0.f};
    const bf16* vtile = vbase + (dq * 16 + fr) * 32 + kg * 8;
    int prow_row = rb * 16 + fr;
    char* prow = smem + prow_row * 4096;
    bf16x8 vb[8], pb[8];
    auto pvload = [&](int kk) {
      vb[kk & 7] = *(const bf16x8*)&vtile[(size_t)kk * (DH * 32)];
      int slotA = kk * 4 + kg;
      pb[kk & 7] = *(const bf16x8*)(prow + ((slotA ^ prow_row) << 4));
    };
    pvload(0);
    pvload(1);
    pvload(2);
    pvload(3);
    __builtin_amdgcn_s_setprio(1);
#pragma unroll
    for (int kk = 0; kk < 64; ++kk) {
      if (kk < 60) pvload(kk + 4);
      cacc = mfma16(pb[kk & 7], vb[kk & 7], cacc);
    }
    __builtin_amdgcn_s_setprio(0);
#pragma unroll
    for (int j = 0; j < 4; ++j) {
      int row = rb * 16 + kg * 4 + j;
      float v = cacc[j] * invp[row];
      ctx[((size_t)b * SS + q0 + row) * DM + h * DH + dq * 16 + fr] = (bf16)v;
    }
  } else {
    int t = (wave - 8) * 64 + lane;  // 0..511
    int slot = t >> 1, halfoff = (t & 1) * 8;
    float* outb = attn_out + ((size_t)bh * SS + q0) * SS;
#pragma unroll 4
    for (int r = 0; r < 32; ++r) {
      bf16x4 e = *(const bf16x4*)(smem + r * 4096 + ((slot ^ r) << 4) + halfoff);
      float inv = invp[r];
      f32x4 u = {(float)e[0] * inv, (float)e[1] * inv, (float)e[2] * inv,
                 (float)e[3] * inv};
      *(f32x4*)(outb + (size_t)r * SS + t * 4) = u;
    }
  }
}

// ---------------- LayerNorm (in-place on y region) ----------------
__global__ __launch_bounds__(256) void ln_k(float* __restrict__ x,
                                            const float* __restrict__ g,
                                            const float* __restrict__ bln) {
  int r = blockIdx.x, tid = threadIdx.x;
  f32x4 v = *(const f32x4*)&x[(size_t)r * DM + tid * 4];
  float s = v[0] + v[1] + v[2] + v[3];
  float s2 = v[0] * v[0] + v[1] * v[1] + v[2] * v[2] + v[3] * v[3];
#pragma unroll
  for (int off = 32; off; off >>= 1) {
    s += __shfl_down(s, off);
    s2 += __shfl_down(s2, off);
  }
  __shared__ float rs_[4], rs2_[4];
  int wave = tid >> 6, lane = tid & 63;
  if (lane == 0) {
    rs_[wave] = s;
    rs2_[wave] = s2;
  }
  __syncthreads();
  s = rs_[0] + rs_[1] + rs_[2] + rs_[3];
  s2 = rs2_[0] + rs2_[1] + rs2_[2] + rs2_[3];
  float mu = s * (1.f / DM);
  float var = s2 * (1.f / DM) - mu * mu;
  float rstd = rsqrtf(var + 1e-5f);
  f32x4 gg = *(const f32x4*)&g[tid * 4];
  f32x4 bb = *(const f32x4*)&bln[tid * 4];
  f32x4 o;
#pragma unroll
  for (int i = 0; i < 4; ++i) o[i] = (v[i] - mu) * rstd * gg[i] + bb[i];
  *(f32x4*)&x[(size_t)r * DM + tid * 4] = o;
}

extern "C" void kernel_launch(void* const* d_in, const int* in_sizes, int n_in,
                              void* d_out, int out_size, void* d_ws,
                              size_t ws_size, hipStream_t stream) {
  const float* q = (const float*)d_in[0];
  const float* k = (const float*)d_in[1];
  const float* v = (const float*)d_in[2];
  const int* mask = (const int*)d_in[3];
  const float* w_q = (const float*)d_in[4];
  const float* b_q = (const float*)d_in[5];
  const float* w_k = (const float*)d_in[6];
  const float* b_k = (const float*)d_in[7];
  const float* w_v = (const float*)d_in[8];
  const float* b_v = (const float*)d_in[9];
  const float* w_fc = (const float*)d_in[10];
  const float* b_fc = (const float*)d_in[11];
  const float* ln_g = (const float*)d_in[12];
  const float* ln_b = (const float*)d_in[13];

  float* y = (float*)d_out;                           // [8192][1024] fp32
  float* attn_out = (float*)d_out + (size_t)MM * DM;  // [64][2048][2048] fp32

  char* w = (char*)d_ws;
  const size_t actN = (size_t)MM * DM;  // 8388608
  bf16* qkv_bf = (bf16*)w;  w += 3 * actN * 2;            // q,k,v bf16
  bf16* wT = (bf16*)w;      w += (size_t)4 * DM * DM * 2; // wq,wk,wv,wfc ^T
  bf16* qhh = (bf16*)w;     w += actN * 2;
  bf16* khh = (bf16*)w;     w += actN * 2;
  bf16* vhT = (bf16*)w;     w += actN * 2;
  bf16* ctx = (bf16*)w;     w += actN * 2;
  unsigned int* mT = (unsigned int*)w;  w += (size_t)BB * 64 * SS * 4;

  // 0. transposed mask bitmask (2 MB, L2-resident)
  mask_bitsT<<<dim3(SS / 32, BB), 256, 0, stream>>>(mask, mT);
  // 1. convert activations
  cvt3<<<dim3(4096, 3), 256, 0, stream>>>(q, k, v, qkv_bf);
  // 2. transpose+convert all 4 weights
  wtrans4<<<dim3(DM / 32, DM / 32, 4), 256, 0, stream>>>(w_q, w_k, w_v, w_fc, wT);
  // 3. fused QKV projection (Q pre-scaled, V tiled-transposed)
  gemm_qkv<<<dim3(MM / 128, 3072 / 128), 256, 0, stream>>>(
      qkv_bf, wT, b_q, b_k, b_v, qhh, khh, vhT);
  // 4. fused attention: wave-specialized PV/store overlap
  hipFuncSetAttribute((const void*)attn_kernel,
                      hipFuncAttributeMaxDynamicSharedMemorySize, 131200);
  attn_kernel<<<4096, 1024, 131200, stream>>>(
      qhh, khh, vhT, mT, attn_out, ctx);
  // 5. output projection + bias + residual
  gemm_out<<<dim3(MM / 128, DM / 128), 256, 0, stream>>>(
      ctx, wT + (size_t)3 * DM * DM, b_fc, q, y);
  // 6. LayerNorm in place
  ln_k<<<MM, 256, 0, stream>>>(y, ln_g, ln_b);
}